// Round 2
// baseline (506.017 us; speedup 1.0000x reference)
//
#include <hip/hip_runtime.h>
#include <hip/hip_bf16.h>
#include <hip/hip_fp16.h>

// DownEdgeMP, round 6: persistent barrier-free angle kernel.
// Theory: r4/r5 angle_mlp was latency-bound on the 11-barrier-per-block chain
// (vmcnt(0) drains x 3 blocks/CU only), NOT atomics (r5 halved them: no change).
// New angle: 1 block/CU (grid 256 x 512thr), W0 (80KB) in LDS once, then each
// wave independently grid-strides 16-edge tiles with ZERO barriers:
//   gather(t+1 prefetched) -> L0(W0 LDS) -> selu/transpose (wave-private hbuf)
//   -> L1/L2 (W1/W2 B-frags direct from global, L1/L2-hot) -> pk-f16 scatter.
// edge MLP unchanged (13us). Weights: bf16 W^T[128][KP], 16B-block XOR(n&7).

using u16    = unsigned short;
using u16x8  = __attribute__((ext_vector_type(8))) unsigned short;
using bf16x8 = __attribute__((ext_vector_type(8))) short;
using f32x4  = __attribute__((ext_vector_type(4))) float;

constexpr int H   = 128;
constexpr int NTH = 256;

__device__ __forceinline__ u16 f2bf(float f) {          // prep only
    union { float f; unsigned u; } x; x.f = f;
    unsigned r = x.u + 0x7FFFu + ((x.u >> 16) & 1u);
    return (u16)(r >> 16);
}
__device__ __forceinline__ unsigned cvt2(float x, float y) {
    union { __hip_bfloat162 h; unsigned u; } c;
    c.h = __float22bfloat162_rn(make_float2(x, y));     // v_cvt_pk_bf16_f32
    return c.u;
}
__device__ __forceinline__ bf16x8 cvt8(float4 a, float4 b) {
    union { unsigned u[4]; bf16x8 v; } o;
    o.u[0] = cvt2(a.x, a.y); o.u[1] = cvt2(a.z, a.w);
    o.u[2] = cvt2(b.x, b.y); o.u[3] = cvt2(b.z, b.w);
    return o.v;
}
__device__ __forceinline__ float4 ld4(const float* p) { return *(const float4*)p; }
__device__ __forceinline__ float h2f(u16 u) {
    union { u16 u; __half h; } c; c.u = u;
    return __half2float(c.h);
}
__device__ __forceinline__ float selu_f(float x) {
    const float scale = 1.0507009873554804934193349852946f;
    const float sa    = 1.0507009873554805f * 1.6732632423543772848170429916717f;
    return x > 0.0f ? scale * x : sa * (__expf(x) - 1.0f);
}

// ---- weight chunk staging (edge_mlp path): 128 rows x 64 k (16 KB) ----
__device__ __forceinline__ void load_wchunk(const u16* __restrict__ wt, int KPu, int c,
                                            int tid, u16x8 st[4]) {
#pragma unroll
    for (int s = 0; s < 4; ++s) {
        int i = s * NTH + tid;                 // 0..1023
        int n = i >> 3, jj = i & 7;
        st[s] = *(const u16x8*)(wt + (size_t)n * KPu + (c * 8 + jj) * 8);
    }
}
__device__ __forceinline__ void write_wchunk(u16* wb, int tid, const u16x8 st[4]) {
#pragma unroll
    for (int s = 0; s < 4; ++s) {
        int i = s * NTH + tid;
        *(u16x8*)(wb + i * 8) = st[s];
    }
}

template<int NKS>
__device__ __forceinline__ void mfma_chunk(const u16* cur, const bf16x8* afc,
                                           int ml, int kq, f32x4 acc[8]) {
#pragma unroll
    for (int ks = 0; ks < NKS; ++ks) {
        bf16x8 a = afc[ks];
#pragma unroll
        for (int sc = 0; sc < 8; ++sc) {
            bf16x8 b = *(const bf16x8*)&cur[(sc * 16 + ml) * 64 +
                                            (((ks * 4 + kq) ^ (ml & 7)) << 3)];
            acc[sc] = __builtin_amdgcn_mfma_f32_16x16x32_bf16(a, b, acc[sc], 0, 0, 0);
        }
    }
}

// W0-style: stream NCHUNK 64-K chunks through double-buffered LDS (edge path).
template<int NCHUNK, int LAST_NKS>
__device__ __forceinline__ void stream_layer(const u16* __restrict__ wt, int KPu,
                                             const bf16x8* af, u16* wb0, u16* wb1,
                                             int tid, int ml, int kq, f32x4 acc[8]) {
    u16x8 st[4];
    load_wchunk(wt, KPu, 0, tid, st);
    write_wchunk(wb0, tid, st);
    __syncthreads();
#pragma unroll
    for (int c = 0; c < NCHUNK; ++c) {
        u16* cur = (c & 1) ? wb1 : wb0;
        u16* nxt = (c & 1) ? wb0 : wb1;
        if (c + 1 < NCHUNK) load_wchunk(wt, KPu, c + 1, tid, st);   // issue early
        if (c == NCHUNK - 1) mfma_chunk<LAST_NKS>(cur, af + 2 * c, ml, kq, acc);
        else                 mfma_chunk<2>(cur, af + 2 * c, ml, kq, acc);
        if (c + 1 < NCHUNK) write_wchunk(nxt, tid, st);             // write late
        __syncthreads();
    }
}

// K=128 layer: preload both 64-K chunks, single barrier (edge path).
__device__ __forceinline__ void preload2_layer(const u16* __restrict__ wt,
                                               const bf16x8* af, u16* wb0, u16* wb1,
                                               int tid, int ml, int kq, f32x4 acc[8]) {
    u16x8 s0[4], s1[4];
    load_wchunk(wt, 128, 0, tid, s0);
    load_wchunk(wt, 128, 1, tid, s1);
    write_wchunk(wb0, tid, s0);
    write_wchunk(wb1, tid, s1);
    __syncthreads();
    mfma_chunk<2>(wb0, af + 0, ml, kq, acc);
    mfma_chunk<2>(wb1, af + 2, ml, kq, acc);
}

__device__ __forceinline__ void init_acc(const float* __restrict__ b, int ml, f32x4 acc[8]) {
#pragma unroll
    for (int sc = 0; sc < 8; ++sc) {
        float bv = b[sc * 16 + ml];
        acc[sc] = f32x4{bv, bv, bv, bv};
    }
}

// SELU(acc) -> bf16 -> hbuf[.][136] (padded stride: b128 reads hit 8-cyc floor)
__device__ __forceinline__ void store_h_selu(const f32x4 acc[8], u16* hbuf,
                                             int w, int ml, int kq) {
#pragma unroll
    for (int sc = 0; sc < 8; ++sc)
#pragma unroll
        for (int r = 0; r < 4; r += 2) {
            unsigned u = cvt2(selu_f(acc[sc][r]), selu_f(acc[sc][r + 1]));
            int rowb = w * 16 + kq * 4 + r;
            hbuf[rowb * 136 + sc * 16 + ml]       = (u16)u;
            hbuf[(rowb + 1) * 136 + sc * 16 + ml] = (u16)(u >> 16);
        }
}
__device__ __forceinline__ void read_af_h(const u16* hbuf, int w, int ml, int kq,
                                          bf16x8 af[4]) {
#pragma unroll
    for (int f = 0; f < 4; ++f)            // col = f*32 + kq*8
        af[f] = *(const bf16x8*)&hbuf[(w * 16 + ml) * 136 + f * 32 + kq * 8];
}

// ---- prep: fp32 W[K][128] -> bf16 W^T[128][KP], 16B-block XOR(n&7) swizzle ----
__global__ void prep_weights(const float* __restrict__ aW0, const float* __restrict__ aW1,
                             const float* __restrict__ aW2, const float* __restrict__ eW0,
                             const float* __restrict__ eW1, const float* __restrict__ eW2,
                             u16* __restrict__ dst)
{
    int t = blockIdx.x * 256 + threadIdx.x;
    const int nbs[6]  = {40, 16, 16, 32, 16, 16};
    const int Ks[6]   = {264, 128, 128, 256, 128, 128};
    const int offs[6] = {0, 40960, 57344, 73728, 106496, 122880};
    const float* Ws[6] = {aW0, aW1, aW2, eW0, eW1, eW2};
    int m = 0, rem = t;
    for (m = 0; m < 6; ++m) { int c = 128 * nbs[m]; if (rem < c) break; rem -= c; }
    if (m >= 6) return;
    const int nb = nbs[m];
    const int n = rem / nb, j = rem % nb;
    const int c = j >> 3, jj = j & 7;
    const int kb = jj ^ (n & 7);
    const int k0 = c * 64 + kb * 8;
    const int K = Ks[m];
    const float* W = Ws[m];
    union { u16 u[8]; u16x8 v; } o;
#pragma unroll
    for (int i = 0; i < 8; ++i) {
        int k = k0 + i;
        o.u[i] = (k < K) ? f2bf(W[k * H + n]) : (u16)0;
    }
    *(u16x8*)&dst[offs[m] + n * (nb * 8) + j * 8] = o.v;
}

// ---- angle persistent kernel helpers ----
__device__ __forceinline__ void issue_gather(float4 r[18],
        const float* __restrict__ e1, const float* __restrict__ e2,
        const float* __restrict__ a12, int e, int rw, int cl, int kq) {
    const float* p1 = e1 + (size_t)rw * H;
    const float* p2 = e2 + (size_t)cl * H;
#pragma unroll
    for (int f = 0; f < 8; ++f) {
        int k0 = f * 32 + kq * 8;
        const float* p = (k0 == 0) ? (a12 + (size_t)e * 8)
                       : (k0 <= 128 ? p1 + (k0 - 8) : p2 + (k0 - 136));
        r[2 * f]     = ld4(p);
        r[2 * f + 1] = ld4(p + 4);
    }
    if (kq == 0) { r[16] = ld4(p2 + 120); r[17] = ld4(p2 + 124); }
}
__device__ __forceinline__ void conv_gather(const float4 r[18], bf16x8 af[9], int kq) {
#pragma unroll
    for (int f = 0; f < 8; ++f) af[f] = cvt8(r[2 * f], r[2 * f + 1]);
    if (kq == 0) af[8] = cvt8(r[16], r[17]);
    else { bf16x8 z = {0,0,0,0,0,0,0,0}; af[8] = z; }
}

// L0: K=288 (264 padded), B-frags from full-W0 LDS (prep layout, rows of 320)
__device__ __forceinline__ void layer0_lds(const u16* w0s, const bf16x8 af[9],
                                           int ml, int kq, f32x4 acc[8]) {
#pragma unroll
    for (int ks = 0; ks < 9; ++ks) {
        int B = ks * 4 + kq;
        int off = ((B >> 3) * 8 + ((B & 7) ^ (ml & 7))) * 8;
#pragma unroll
        for (int sc = 0; sc < 8; ++sc) {
            bf16x8 b = *(const bf16x8*)&w0s[(sc * 16 + ml) * 320 + off];
            acc[sc] = __builtin_amdgcn_mfma_f32_16x16x32_bf16(af[ks], b, acc[sc], 0, 0, 0);
        }
    }
}
// K=128 layer with B-frags read directly from global (L1/L2-hot 32 KB)
__device__ __forceinline__ void layer_gw(const u16* __restrict__ wt,
                                         const bf16x8 afx[4], int ml, int kq,
                                         f32x4 acc[8]) {
#pragma unroll
    for (int ks = 0; ks < 4; ++ks) {
        int B = ks * 4 + kq;
        int off = ((B >> 3) * 8 + ((B & 7) ^ (ml & 7))) * 8;
#pragma unroll
        for (int sc = 0; sc < 8; ++sc) {
            bf16x8 b = *(const bf16x8*)&wt[(sc * 16 + ml) * 128 + off];
            acc[sc] = __builtin_amdgcn_mfma_f32_16x16x32_bf16(afx[ks], b, acc[sc], 0, 0, 0);
        }
    }
}

// ---- angle MLP: persistent, barrier-free steady state ----
__global__ __launch_bounds__(512, 2) void angle_mlp(
    const float* __restrict__ e1, const float* __restrict__ e2,
    const float* __restrict__ a12, const int* __restrict__ idx,
    const u16* __restrict__ wt0, const u16* __restrict__ wt1, const u16* __restrict__ wt2,
    const float* __restrict__ b0, const float* __restrict__ b1, const float* __restrict__ b2,
    u16* __restrict__ sums, float* __restrict__ cnt, int A)
{
    __shared__ u16 w0s[128 * 320];      // 80 KB, full W0 (prep layout)
    __shared__ u16 hbuf[128 * 136];     // 34 KB, 8 wave-private 16-row slices

    const int tid = threadIdx.x;
#pragma unroll
    for (int i = 0; i < 10; ++i) {      // 5120 u16x8 / 512 threads
        int j = i * 512 + tid;
        *(u16x8*)&w0s[j * 8] = *(const u16x8*)&wt0[j * 8];
    }
    __syncthreads();                    // only barrier in the kernel

    const int lane = tid & 63;
    const int ml = lane & 15, kq = lane >> 4;
    const int wv = tid >> 6;            // 0..7
    u16* hb = hbuf + wv * (16 * 136);

    const int NT = A >> 4;              // 25000 tiles of 16 edges
    int t = blockIdx.x * 8 + wv;        // 0..2047

    int e = t * 16 + ml;
    int rw = idx[e];
    int cl = idx[A + e];
    float4 raw[18];
    issue_gather(raw, e1, e2, a12, e, rw, cl, kq);

    while (true) {
        const int tn = t + 2048;
        const bool last = tn >= NT;     // wave-uniform

        bf16x8 af[9];
        conv_gather(raw, af, kq);       // waits on prefetched gather
        if (kq == 0) atomicAdd(&cnt[cl], 1.0f);

        int en = e, rwn = rw, cln = cl;
        if (!last) { en = tn * 16 + ml; rwn = idx[en]; cln = idx[A + en]; }

        f32x4 acc[8];
        init_acc(b0, ml, acc);
        layer0_lds(w0s, af, ml, kq, acc);

        if (!last) issue_gather(raw, e1, e2, a12, en, rwn, cln, kq);  // hide HBM lat

        store_h_selu(acc, hb, 0, ml, kq);       // wave-private: no barrier
        bf16x8 af1[4];
        read_af_h(hb, 0, ml, kq, af1);
        init_acc(b1, ml, acc);
        layer_gw(wt1, af1, ml, kq, acc);

        store_h_selu(acc, hb, 0, ml, kq);
        bf16x8 af2[4];
        read_af_h(hb, 0, ml, kq, af2);
        init_acc(b2, ml, acc);
        layer_gw(wt2, af2, ml, kq, acc);

        // scatter tile t via packed-f16 atomics (acc already includes bias).
        {
            const int rb = (ml & 1) * 2;
            const size_t i0 = (size_t)A + (size_t)t * 16 + kq * 4;
            const int clr0 = idx[i0 + rb];
            const int clr1 = idx[i0 + rb + 1];
#pragma unroll
            for (int sc = 0; sc < 8; ++sc) {
                float p0 = __shfl_xor(acc[sc][0], 1);
                float p1 = __shfl_xor(acc[sc][1], 1);
                float p2 = __shfl_xor(acc[sc][2], 1);
                float p3 = __shfl_xor(acc[sc][3], 1);
                float o0 = acc[sc][rb], o1 = acc[sc][rb + 1];
                float q0 = (ml & 1) ? p2 : p0;          // partner col, my rows
                float q1 = (ml & 1) ? p3 : p1;
                float l0 = (ml & 1) ? q0 : o0, h0 = (ml & 1) ? o0 : q0;
                float l1 = (ml & 1) ? q1 : o1, h1 = (ml & 1) ? o1 : q1;
                union { __half2 h; unsigned u; } c0, c1;
                c0.h = __floats2half2_rn(l0, h0);
                c1.h = __floats2half2_rn(l1, h1);
                u16* d0 = sums + (size_t)clr0 * H + sc * 16 + (ml & ~1);
                u16* d1 = sums + (size_t)clr1 * H + sc * 16 + (ml & ~1);
                asm volatile("global_atomic_pk_add_f16 %0, %1, off" :: "v"(d0), "v"(c0.u) : "memory");
                asm volatile("global_atomic_pk_add_f16 %0, %1, off" :: "v"(d1), "v"(c1.u) : "memory");
            }
        }

        if (last) break;
        t = tn; e = en; rw = rwn; cl = cln;
    }
}

// ---- edge MLP (unchanged r5 structure, f16 sums input) ----
__global__ __launch_bounds__(NTH, 3) void edge_mlp(
    const float* __restrict__ e2, const u16* __restrict__ sums,
    const float* __restrict__ cnt,
    const u16* __restrict__ wt0, const u16* __restrict__ wt1, const u16* __restrict__ wt2,
    const float* __restrict__ b0, const float* __restrict__ b1, const float* __restrict__ b2,
    float* __restrict__ out, int E2n)
{
    __shared__ u16 wbuf[2][128 * 64];
    __shared__ u16 hbuf[64 * 136];

    const int tid = threadIdx.x;
    const int lane = tid & 63;
    const int ml = lane & 15, kq = lane >> 4;
    const int w = tid >> 6;
    const int nbase = blockIdx.x * 64;
    const int node = nbase + w * 16 + ml;
    const int nc = node < E2n ? node : E2n - 1;

    const float rcp = 1.0f / fmaxf(cnt[nc], 1.0f);
    // frag f: k0 = f*32 + kq*8; k0<128 -> f16 sums*rcp | else e2[k0-128]
    bf16x8 af[8];
    {
        const u16* ps = sums + (size_t)nc * H;
        const float* p2 = e2 + (size_t)nc * H;
#pragma unroll
        for (int f = 0; f < 8; ++f) {
            int k0 = f * 32 + kq * 8;
            float4 lo, hi;
            if (k0 < 128) {
                u16x8 hv = *(const u16x8*)(ps + k0);
                lo.x = h2f(hv[0]) * rcp; lo.y = h2f(hv[1]) * rcp;
                lo.z = h2f(hv[2]) * rcp; lo.w = h2f(hv[3]) * rcp;
                hi.x = h2f(hv[4]) * rcp; hi.y = h2f(hv[5]) * rcp;
                hi.z = h2f(hv[6]) * rcp; hi.w = h2f(hv[7]) * rcp;
            } else {
                lo = ld4(p2 + (k0 - 128));
                hi = ld4(p2 + (k0 - 124));
            }
            af[f] = cvt8(lo, hi);
        }
    }

    f32x4 acc[8];
    init_acc(b0, ml, acc);
    stream_layer<4, 2>(wt0, 256, af, wbuf[0], wbuf[1], tid, ml, kq, acc);

    store_h_selu(acc, hbuf, w, ml, kq);
    __syncthreads();
    bf16x8 af1[4];
    read_af_h(hbuf, w, ml, kq, af1);
    init_acc(b1, ml, acc);
    preload2_layer(wt1, af1, wbuf[0], wbuf[1], tid, ml, kq, acc);

    __syncthreads();
    store_h_selu(acc, hbuf, w, ml, kq);
    __syncthreads();
    bf16x8 af2[4];
    read_af_h(hbuf, w, ml, kq, af2);
    init_acc(b2, ml, acc);
    preload2_layer(wt2, af2, wbuf[0], wbuf[1], tid, ml, kq, acc);

#pragma unroll
    for (int r = 0; r < 4; ++r) {
        int nrow = nbase + w * 16 + kq * 4 + r;
        if (nrow < E2n) {
            float* dst = out + (size_t)nrow * H + ml;
#pragma unroll
            for (int sc = 0; sc < 8; ++sc)
                dst[sc * 16] = acc[sc][r];
        }
    }
}

extern "C" void kernel_launch(void* const* d_in, const int* in_sizes, int n_in,
                              void* d_out, int out_size, void* d_ws, size_t ws_size,
                              hipStream_t stream)
{
    const float* e1  = (const float*)d_in[0];
    const float* e2  = (const float*)d_in[1];
    const float* a12 = (const float*)d_in[2];
    const int*   idx = (const int*)d_in[3];
    const float* aW0 = (const float*)d_in[4];
    const float* ab0 = (const float*)d_in[5];
    const float* aW1 = (const float*)d_in[6];
    const float* ab1 = (const float*)d_in[7];
    const float* aW2 = (const float*)d_in[8];
    const float* ab2 = (const float*)d_in[9];
    const float* eW0 = (const float*)d_in[10];
    const float* eb0 = (const float*)d_in[11];
    const float* eW1 = (const float*)d_in[12];
    const float* eb1 = (const float*)d_in[13];
    const float* eW2 = (const float*)d_in[14];
    const float* eb2 = (const float*)d_in[15];

    const int E2n = in_sizes[1] / H;   // 100000
    const int A   = in_sizes[2] / 8;   // 400000

    char* ws = (char*)d_ws;
    u16*   wdst   = (u16*)ws;                                // 278528 B
    u16*   sums_h = (u16*)(ws + 278528);                     // f16 [E2][128]
    float* cnt    = (float*)(ws + 278528 + (size_t)E2n * H * 2);

    hipMemsetAsync(sums_h, 0, (size_t)E2n * H * 2 + (size_t)E2n * 4, stream);
    prep_weights<<<dim3(68), dim3(256), 0, stream>>>(aW0, aW1, aW2, eW0, eW1, eW2, wdst);

    angle_mlp<<<dim3(256), dim3(512), 0, stream>>>(
        e1, e2, a12, idx, wdst + 0, wdst + 40960, wdst + 57344,
        ab0, ab1, ab2, sums_h, cnt, A);

    edge_mlp<<<dim3((E2n + 63) / 64), dim3(NTH), 0, stream>>>(
        e2, sums_h, cnt, wdst + 73728, wdst + 106496, wdst + 122880,
        eb0, eb1, eb2, (float*)d_out, E2n);
}

// Round 3
// 484.715 us; speedup vs baseline: 1.0439x; 1.0439x over previous
//
#include <hip/hip_runtime.h>
#include <hip/hip_bf16.h>
#include <hip/hip_fp16.h>

// DownEdgeMP, round 7: persistent barrier-free angle kernel, spill fix.
// r6 post-mortem: __launch_bounds__(512,2) capped VGPR at 128 (4 waves/SIMD
// target) -> raw[18] prefetch spilled to scratch -> FETCH 205->983MB, 478us.
// LDS (114KB) limits to 1 block/CU regardless, so the cap bought nothing.
// Fix: __launch_bounds__(512,1) -> 256-VGPR budget, no spill; everything else
// identical to r6: 1 block/CU (grid 256 x 512thr), W0 (80KB) in LDS once, each
// wave independently grid-strides 16-edge tiles with ZERO steady-state barriers:
//   gather(t+1 prefetched in regs) -> L0(W0 LDS) -> selu/transpose (wave-private
//   hbuf) -> L1/L2 (W1/W2 B-frags direct from global, L2-hot) -> pk-f16 scatter.

using u16    = unsigned short;
using u16x8  = __attribute__((ext_vector_type(8))) unsigned short;
using bf16x8 = __attribute__((ext_vector_type(8))) short;
using f32x4  = __attribute__((ext_vector_type(4))) float;

constexpr int H   = 128;
constexpr int NTH = 256;

__device__ __forceinline__ u16 f2bf(float f) {          // prep only
    union { float f; unsigned u; } x; x.f = f;
    unsigned r = x.u + 0x7FFFu + ((x.u >> 16) & 1u);
    return (u16)(r >> 16);
}
__device__ __forceinline__ unsigned cvt2(float x, float y) {
    union { __hip_bfloat162 h; unsigned u; } c;
    c.h = __float22bfloat162_rn(make_float2(x, y));     // v_cvt_pk_bf16_f32
    return c.u;
}
__device__ __forceinline__ bf16x8 cvt8(float4 a, float4 b) {
    union { unsigned u[4]; bf16x8 v; } o;
    o.u[0] = cvt2(a.x, a.y); o.u[1] = cvt2(a.z, a.w);
    o.u[2] = cvt2(b.x, b.y); o.u[3] = cvt2(b.z, b.w);
    return o.v;
}
__device__ __forceinline__ float4 ld4(const float* p) { return *(const float4*)p; }
__device__ __forceinline__ float h2f(u16 u) {
    union { u16 u; __half h; } c; c.u = u;
    return __half2float(c.h);
}
__device__ __forceinline__ float selu_f(float x) {
    const float scale = 1.0507009873554804934193349852946f;
    const float sa    = 1.0507009873554805f * 1.6732632423543772848170429916717f;
    return x > 0.0f ? scale * x : sa * (__expf(x) - 1.0f);
}

// ---- weight chunk staging (edge_mlp path): 128 rows x 64 k (16 KB) ----
__device__ __forceinline__ void load_wchunk(const u16* __restrict__ wt, int KPu, int c,
                                            int tid, u16x8 st[4]) {
#pragma unroll
    for (int s = 0; s < 4; ++s) {
        int i = s * NTH + tid;                 // 0..1023
        int n = i >> 3, jj = i & 7;
        st[s] = *(const u16x8*)(wt + (size_t)n * KPu + (c * 8 + jj) * 8);
    }
}
__device__ __forceinline__ void write_wchunk(u16* wb, int tid, const u16x8 st[4]) {
#pragma unroll
    for (int s = 0; s < 4; ++s) {
        int i = s * NTH + tid;
        *(u16x8*)(wb + i * 8) = st[s];
    }
}

template<int NKS>
__device__ __forceinline__ void mfma_chunk(const u16* cur, const bf16x8* afc,
                                           int ml, int kq, f32x4 acc[8]) {
#pragma unroll
    for (int ks = 0; ks < NKS; ++ks) {
        bf16x8 a = afc[ks];
#pragma unroll
        for (int sc = 0; sc < 8; ++sc) {
            bf16x8 b = *(const bf16x8*)&cur[(sc * 16 + ml) * 64 +
                                            (((ks * 4 + kq) ^ (ml & 7)) << 3)];
            acc[sc] = __builtin_amdgcn_mfma_f32_16x16x32_bf16(a, b, acc[sc], 0, 0, 0);
        }
    }
}

// W0-style: stream NCHUNK 64-K chunks through double-buffered LDS (edge path).
template<int NCHUNK, int LAST_NKS>
__device__ __forceinline__ void stream_layer(const u16* __restrict__ wt, int KPu,
                                             const bf16x8* af, u16* wb0, u16* wb1,
                                             int tid, int ml, int kq, f32x4 acc[8]) {
    u16x8 st[4];
    load_wchunk(wt, KPu, 0, tid, st);
    write_wchunk(wb0, tid, st);
    __syncthreads();
#pragma unroll
    for (int c = 0; c < NCHUNK; ++c) {
        u16* cur = (c & 1) ? wb1 : wb0;
        u16* nxt = (c & 1) ? wb0 : wb1;
        if (c + 1 < NCHUNK) load_wchunk(wt, KPu, c + 1, tid, st);   // issue early
        if (c == NCHUNK - 1) mfma_chunk<LAST_NKS>(cur, af + 2 * c, ml, kq, acc);
        else                 mfma_chunk<2>(cur, af + 2 * c, ml, kq, acc);
        if (c + 1 < NCHUNK) write_wchunk(nxt, tid, st);             // write late
        __syncthreads();
    }
}

// K=128 layer: preload both 64-K chunks, single barrier (edge path).
__device__ __forceinline__ void preload2_layer(const u16* __restrict__ wt,
                                               const bf16x8* af, u16* wb0, u16* wb1,
                                               int tid, int ml, int kq, f32x4 acc[8]) {
    u16x8 s0[4], s1[4];
    load_wchunk(wt, 128, 0, tid, s0);
    load_wchunk(wt, 128, 1, tid, s1);
    write_wchunk(wb0, tid, s0);
    write_wchunk(wb1, tid, s1);
    __syncthreads();
    mfma_chunk<2>(wb0, af + 0, ml, kq, acc);
    mfma_chunk<2>(wb1, af + 2, ml, kq, acc);
}

__device__ __forceinline__ void init_acc(const float* __restrict__ b, int ml, f32x4 acc[8]) {
#pragma unroll
    for (int sc = 0; sc < 8; ++sc) {
        float bv = b[sc * 16 + ml];
        acc[sc] = f32x4{bv, bv, bv, bv};
    }
}

// SELU(acc) -> bf16 -> hbuf[.][136] (padded stride: b128 reads hit 8-cyc floor)
__device__ __forceinline__ void store_h_selu(const f32x4 acc[8], u16* hbuf,
                                             int w, int ml, int kq) {
#pragma unroll
    for (int sc = 0; sc < 8; ++sc)
#pragma unroll
        for (int r = 0; r < 4; r += 2) {
            unsigned u = cvt2(selu_f(acc[sc][r]), selu_f(acc[sc][r + 1]));
            int rowb = w * 16 + kq * 4 + r;
            hbuf[rowb * 136 + sc * 16 + ml]       = (u16)u;
            hbuf[(rowb + 1) * 136 + sc * 16 + ml] = (u16)(u >> 16);
        }
}
__device__ __forceinline__ void read_af_h(const u16* hbuf, int w, int ml, int kq,
                                          bf16x8 af[4]) {
#pragma unroll
    for (int f = 0; f < 4; ++f)            // col = f*32 + kq*8
        af[f] = *(const bf16x8*)&hbuf[(w * 16 + ml) * 136 + f * 32 + kq * 8];
}

// ---- prep: fp32 W[K][128] -> bf16 W^T[128][KP], 16B-block XOR(n&7) swizzle ----
__global__ void prep_weights(const float* __restrict__ aW0, const float* __restrict__ aW1,
                             const float* __restrict__ aW2, const float* __restrict__ eW0,
                             const float* __restrict__ eW1, const float* __restrict__ eW2,
                             u16* __restrict__ dst)
{
    int t = blockIdx.x * 256 + threadIdx.x;
    const int nbs[6]  = {40, 16, 16, 32, 16, 16};
    const int Ks[6]   = {264, 128, 128, 256, 128, 128};
    const int offs[6] = {0, 40960, 57344, 73728, 106496, 122880};
    const float* Ws[6] = {aW0, aW1, aW2, eW0, eW1, eW2};
    int m = 0, rem = t;
    for (m = 0; m < 6; ++m) { int c = 128 * nbs[m]; if (rem < c) break; rem -= c; }
    if (m >= 6) return;
    const int nb = nbs[m];
    const int n = rem / nb, j = rem % nb;
    const int c = j >> 3, jj = j & 7;
    const int kb = jj ^ (n & 7);
    const int k0 = c * 64 + kb * 8;
    const int K = Ks[m];
    const float* W = Ws[m];
    union { u16 u[8]; u16x8 v; } o;
#pragma unroll
    for (int i = 0; i < 8; ++i) {
        int k = k0 + i;
        o.u[i] = (k < K) ? f2bf(W[k * H + n]) : (u16)0;
    }
    *(u16x8*)&dst[offs[m] + n * (nb * 8) + j * 8] = o.v;
}

// ---- angle persistent kernel helpers ----
__device__ __forceinline__ void issue_gather(float4 r[18],
        const float* __restrict__ e1, const float* __restrict__ e2,
        const float* __restrict__ a12, int e, int rw, int cl, int kq) {
    const float* p1 = e1 + (size_t)rw * H;
    const float* p2 = e2 + (size_t)cl * H;
#pragma unroll
    for (int f = 0; f < 8; ++f) {
        int k0 = f * 32 + kq * 8;
        const float* p = (k0 == 0) ? (a12 + (size_t)e * 8)
                       : (k0 <= 128 ? p1 + (k0 - 8) : p2 + (k0 - 136));
        r[2 * f]     = ld4(p);
        r[2 * f + 1] = ld4(p + 4);
    }
    if (kq == 0) { r[16] = ld4(p2 + 120); r[17] = ld4(p2 + 124); }
}
__device__ __forceinline__ void conv_gather(const float4 r[18], bf16x8 af[9], int kq) {
#pragma unroll
    for (int f = 0; f < 8; ++f) af[f] = cvt8(r[2 * f], r[2 * f + 1]);
    if (kq == 0) af[8] = cvt8(r[16], r[17]);
    else { bf16x8 z = {0,0,0,0,0,0,0,0}; af[8] = z; }
}

// L0: K=288 (264 padded), B-frags from full-W0 LDS (prep layout, rows of 320)
__device__ __forceinline__ void layer0_lds(const u16* w0s, const bf16x8 af[9],
                                           int ml, int kq, f32x4 acc[8]) {
#pragma unroll
    for (int ks = 0; ks < 9; ++ks) {
        int B = ks * 4 + kq;
        int off = ((B >> 3) * 8 + ((B & 7) ^ (ml & 7))) * 8;
#pragma unroll
        for (int sc = 0; sc < 8; ++sc) {
            bf16x8 b = *(const bf16x8*)&w0s[(sc * 16 + ml) * 320 + off];
            acc[sc] = __builtin_amdgcn_mfma_f32_16x16x32_bf16(af[ks], b, acc[sc], 0, 0, 0);
        }
    }
}
// K=128 layer with B-frags read directly from global (L2-hot 32 KB)
__device__ __forceinline__ void layer_gw(const u16* __restrict__ wt,
                                         const bf16x8 afx[4], int ml, int kq,
                                         f32x4 acc[8]) {
#pragma unroll
    for (int ks = 0; ks < 4; ++ks) {
        int B = ks * 4 + kq;
        int off = ((B >> 3) * 8 + ((B & 7) ^ (ml & 7))) * 8;
#pragma unroll
        for (int sc = 0; sc < 8; ++sc) {
            bf16x8 b = *(const bf16x8*)&wt[(sc * 16 + ml) * 128 + off];
            acc[sc] = __builtin_amdgcn_mfma_f32_16x16x32_bf16(afx[ks], b, acc[sc], 0, 0, 0);
        }
    }
}

// ---- angle MLP: persistent, barrier-free steady state ----
// launch_bounds(512,1): 8-wave block => HW enforces <=256 VGPR; LDS already
// limits to 1 block/CU, so no occupancy is lost vs the (512,2) spill version.
__global__ __launch_bounds__(512, 1) void angle_mlp(
    const float* __restrict__ e1, const float* __restrict__ e2,
    const float* __restrict__ a12, const int* __restrict__ idx,
    const u16* __restrict__ wt0, const u16* __restrict__ wt1, const u16* __restrict__ wt2,
    const float* __restrict__ b0, const float* __restrict__ b1, const float* __restrict__ b2,
    u16* __restrict__ sums, float* __restrict__ cnt, int A)
{
    __shared__ u16 w0s[128 * 320];      // 80 KB, full W0 (prep layout)
    __shared__ u16 hbuf[128 * 136];     // 34 KB, 8 wave-private 16-row slices

    const int tid = threadIdx.x;
#pragma unroll
    for (int i = 0; i < 10; ++i) {      // 5120 u16x8 / 512 threads
        int j = i * 512 + tid;
        *(u16x8*)&w0s[j * 8] = *(const u16x8*)&wt0[j * 8];
    }
    __syncthreads();                    // only barrier in the kernel

    const int lane = tid & 63;
    const int ml = lane & 15, kq = lane >> 4;
    const int wv = tid >> 6;            // 0..7
    u16* hb = hbuf + wv * (16 * 136);

    const int NT = A >> 4;              // 25000 tiles of 16 edges
    int t = blockIdx.x * 8 + wv;        // 0..2047

    int e = t * 16 + ml;
    int rw = idx[e];
    int cl = idx[A + e];
    float4 raw[18];
    issue_gather(raw, e1, e2, a12, e, rw, cl, kq);

    while (true) {
        const int tn = t + 2048;
        const bool last = tn >= NT;     // wave-uniform

        bf16x8 af[9];
        conv_gather(raw, af, kq);       // waits on prefetched gather
        if (kq == 0) atomicAdd(&cnt[cl], 1.0f);

        int en = e, rwn = rw, cln = cl;
        if (!last) { en = tn * 16 + ml; rwn = idx[en]; cln = idx[A + en]; }

        f32x4 acc[8];
        init_acc(b0, ml, acc);
        layer0_lds(w0s, af, ml, kq, acc);

        if (!last) issue_gather(raw, e1, e2, a12, en, rwn, cln, kq);  // hide HBM lat

        store_h_selu(acc, hb, 0, ml, kq);       // wave-private: no barrier
        bf16x8 af1[4];
        read_af_h(hb, 0, ml, kq, af1);
        init_acc(b1, ml, acc);
        layer_gw(wt1, af1, ml, kq, acc);

        store_h_selu(acc, hb, 0, ml, kq);
        bf16x8 af2[4];
        read_af_h(hb, 0, ml, kq, af2);
        init_acc(b2, ml, acc);
        layer_gw(wt2, af2, ml, kq, acc);

        // scatter tile t via packed-f16 atomics (acc already includes bias).
        {
            const int rb = (ml & 1) * 2;
            const size_t i0 = (size_t)A + (size_t)t * 16 + kq * 4;
            const int clr0 = idx[i0 + rb];
            const int clr1 = idx[i0 + rb + 1];
#pragma unroll
            for (int sc = 0; sc < 8; ++sc) {
                float p0 = __shfl_xor(acc[sc][0], 1);
                float p1 = __shfl_xor(acc[sc][1], 1);
                float p2 = __shfl_xor(acc[sc][2], 1);
                float p3 = __shfl_xor(acc[sc][3], 1);
                float o0 = acc[sc][rb], o1 = acc[sc][rb + 1];
                float q0 = (ml & 1) ? p2 : p0;          // partner col, my rows
                float q1 = (ml & 1) ? p3 : p1;
                float l0 = (ml & 1) ? q0 : o0, h0 = (ml & 1) ? o0 : q0;
                float l1 = (ml & 1) ? q1 : o1, h1 = (ml & 1) ? o1 : q1;
                union { __half2 h; unsigned u; } c0, c1;
                c0.h = __floats2half2_rn(l0, h0);
                c1.h = __floats2half2_rn(l1, h1);
                u16* d0 = sums + (size_t)clr0 * H + sc * 16 + (ml & ~1);
                u16* d1 = sums + (size_t)clr1 * H + sc * 16 + (ml & ~1);
                asm volatile("global_atomic_pk_add_f16 %0, %1, off" :: "v"(d0), "v"(c0.u) : "memory");
                asm volatile("global_atomic_pk_add_f16 %0, %1, off" :: "v"(d1), "v"(c1.u) : "memory");
            }
        }

        if (last) break;
        t = tn; e = en; rw = rwn; cl = cln;
    }
}

// ---- edge MLP (unchanged r5 structure, f16 sums input) ----
__global__ __launch_bounds__(NTH, 3) void edge_mlp(
    const float* __restrict__ e2, const u16* __restrict__ sums,
    const float* __restrict__ cnt,
    const u16* __restrict__ wt0, const u16* __restrict__ wt1, const u16* __restrict__ wt2,
    const float* __restrict__ b0, const float* __restrict__ b1, const float* __restrict__ b2,
    float* __restrict__ out, int E2n)
{
    __shared__ u16 wbuf[2][128 * 64];
    __shared__ u16 hbuf[64 * 136];

    const int tid = threadIdx.x;
    const int lane = tid & 63;
    const int ml = lane & 15, kq = lane >> 4;
    const int w = tid >> 6;
    const int nbase = blockIdx.x * 64;
    const int node = nbase + w * 16 + ml;
    const int nc = node < E2n ? node : E2n - 1;

    const float rcp = 1.0f / fmaxf(cnt[nc], 1.0f);
    // frag f: k0 = f*32 + kq*8; k0<128 -> f16 sums*rcp | else e2[k0-128]
    bf16x8 af[8];
    {
        const u16* ps = sums + (size_t)nc * H;
        const float* p2 = e2 + (size_t)nc * H;
#pragma unroll
        for (int f = 0; f < 8; ++f) {
            int k0 = f * 32 + kq * 8;
            float4 lo, hi;
            if (k0 < 128) {
                u16x8 hv = *(const u16x8*)(ps + k0);
                lo.x = h2f(hv[0]) * rcp; lo.y = h2f(hv[1]) * rcp;
                lo.z = h2f(hv[2]) * rcp; lo.w = h2f(hv[3]) * rcp;
                hi.x = h2f(hv[4]) * rcp; hi.y = h2f(hv[5]) * rcp;
                hi.z = h2f(hv[6]) * rcp; hi.w = h2f(hv[7]) * rcp;
            } else {
                lo = ld4(p2 + (k0 - 128));
                hi = ld4(p2 + (k0 - 124));
            }
            af[f] = cvt8(lo, hi);
        }
    }

    f32x4 acc[8];
    init_acc(b0, ml, acc);
    stream_layer<4, 2>(wt0, 256, af, wbuf[0], wbuf[1], tid, ml, kq, acc);

    store_h_selu(acc, hbuf, w, ml, kq);
    __syncthreads();
    bf16x8 af1[4];
    read_af_h(hbuf, w, ml, kq, af1);
    init_acc(b1, ml, acc);
    preload2_layer(wt1, af1, wbuf[0], wbuf[1], tid, ml, kq, acc);

    __syncthreads();
    store_h_selu(acc, hbuf, w, ml, kq);
    __syncthreads();
    bf16x8 af2[4];
    read_af_h(hbuf, w, ml, kq, af2);
    init_acc(b2, ml, acc);
    preload2_layer(wt2, af2, wbuf[0], wbuf[1], tid, ml, kq, acc);

#pragma unroll
    for (int r = 0; r < 4; ++r) {
        int nrow = nbase + w * 16 + kq * 4 + r;
        if (nrow < E2n) {
            float* dst = out + (size_t)nrow * H + ml;
#pragma unroll
            for (int sc = 0; sc < 8; ++sc)
                dst[sc * 16] = acc[sc][r];
        }
    }
}

extern "C" void kernel_launch(void* const* d_in, const int* in_sizes, int n_in,
                              void* d_out, int out_size, void* d_ws, size_t ws_size,
                              hipStream_t stream)
{
    const float* e1  = (const float*)d_in[0];
    const float* e2  = (const float*)d_in[1];
    const float* a12 = (const float*)d_in[2];
    const int*   idx = (const int*)d_in[3];
    const float* aW0 = (const float*)d_in[4];
    const float* ab0 = (const float*)d_in[5];
    const float* aW1 = (const float*)d_in[6];
    const float* ab1 = (const float*)d_in[7];
    const float* aW2 = (const float*)d_in[8];
    const float* ab2 = (const float*)d_in[9];
    const float* eW0 = (const float*)d_in[10];
    const float* eb0 = (const float*)d_in[11];
    const float* eW1 = (const float*)d_in[12];
    const float* eb1 = (const float*)d_in[13];
    const float* eW2 = (const float*)d_in[14];
    const float* eb2 = (const float*)d_in[15];

    const int E2n = in_sizes[1] / H;   // 100000
    const int A   = in_sizes[2] / 8;   // 400000

    char* ws = (char*)d_ws;
    u16*   wdst   = (u16*)ws;                                // 278528 B
    u16*   sums_h = (u16*)(ws + 278528);                     // f16 [E2][128]
    float* cnt    = (float*)(ws + 278528 + (size_t)E2n * H * 2);

    hipMemsetAsync(sums_h, 0, (size_t)E2n * H * 2 + (size_t)E2n * 4, stream);
    prep_weights<<<dim3(68), dim3(256), 0, stream>>>(aW0, aW1, aW2, eW0, eW1, eW2, wdst);

    angle_mlp<<<dim3(256), dim3(512), 0, stream>>>(
        e1, e2, a12, idx, wdst + 0, wdst + 40960, wdst + 57344,
        ab0, ab1, ab2, sums_h, cnt, A);

    edge_mlp<<<dim3((E2n + 63) / 64), dim3(NTH), 0, stream>>>(
        e2, sums_h, cnt, wdst + 73728, wdst + 106496, wdst + 122880,
        eb0, eb1, eb2, (float*)d_out, E2n);
}

// Round 4
// 436.596 us; speedup vs baseline: 1.1590x; 1.1102x over previous
//
#include <hip/hip_runtime.h>
#include <hip/hip_bf16.h>
#include <hip/hip_fp16.h>

// DownEdgeMP, round 8: persistent angle kernel, ALL weights in LDS,
// operand-swapped MFMA (A=W^T, B=x^T/h^T) + baked pi-permutation of hidden
// units -> layer transitions are pure in-lane selu+cvt_pk (no hbuf, no shfl).
// r6/r7 post-mortem: 983MB FETCH = W1/W2 global B-frag reads thrashing L2
// against the gather stream (not VGPR spill: (512,1) changed nothing).
// LDS: W0 80KB + W1 32KB + W2 32KB + biases 1KB = 145KB, 1 block/CU, 8 waves,
// zero steady-state barriers, zero steady-state global weight reads.
// pi(p) = 32*(s&3) + 8*kq + 4*(s>>2) + r  (p = 16s + 4kq + r):
//   W0 stores col pi(n) + bias row at k=264 (const-1 input elem);
//   W1 stores W1[k][pi(n)] (input perm cancels: pi(phi(k))=k); W2 canonical.
//   => B-frag for next layer = pack(selu(acc[ks]), selu(acc[ks+4])).
// Scatter: D cols = edges (col=ml) -> per-lane own-edge contiguous pk-f16.

using u16    = unsigned short;
using u16x8  = __attribute__((ext_vector_type(8))) unsigned short;
using bf16x8 = __attribute__((ext_vector_type(8))) short;
using f32x4  = __attribute__((ext_vector_type(4))) float;

constexpr int H   = 128;
constexpr int NTH = 256;

__device__ __forceinline__ u16 f2bf(float f) {          // prep only
    union { float f; unsigned u; } x; x.f = f;
    unsigned r = x.u + 0x7FFFu + ((x.u >> 16) & 1u);
    return (u16)(r >> 16);
}
__device__ __forceinline__ unsigned cvt2(float x, float y) {
    union { __hip_bfloat162 h; unsigned u; } c;
    c.h = __float22bfloat162_rn(make_float2(x, y));     // v_cvt_pk_bf16_f32
    return c.u;
}
__device__ __forceinline__ bf16x8 cvt8(float4 a, float4 b) {
    union { unsigned u[4]; bf16x8 v; } o;
    o.u[0] = cvt2(a.x, a.y); o.u[1] = cvt2(a.z, a.w);
    o.u[2] = cvt2(b.x, b.y); o.u[3] = cvt2(b.z, b.w);
    return o.v;
}
__device__ __forceinline__ float4 ld4(const float* p) { return *(const float4*)p; }
__device__ __forceinline__ float h2f(u16 u) {
    union { u16 u; __half h; } c; c.u = u;
    return __half2float(c.h);
}
__device__ __forceinline__ float selu_f(float x) {
    const float scale = 1.0507009873554804934193349852946f;
    const float sa    = 1.0507009873554805f * 1.6732632423543772848170429916717f;
    return x > 0.0f ? scale * x : sa * (__expf(x) - 1.0f);
}
// pack(selu(a), selu(b)) -> bf16x8 : the entire layer transition
__device__ __forceinline__ bf16x8 cvt8selu(f32x4 a, f32x4 b) {
    union { unsigned u[4]; bf16x8 v; } o;
    o.u[0] = cvt2(selu_f(a[0]), selu_f(a[1]));
    o.u[1] = cvt2(selu_f(a[2]), selu_f(a[3]));
    o.u[2] = cvt2(selu_f(b[0]), selu_f(b[1]));
    o.u[3] = cvt2(selu_f(b[2]), selu_f(b[3]));
    return o.v;
}
__device__ __forceinline__ int pperm(int p) {           // pi
    int s = p >> 4, kq = (p >> 2) & 3, r = p & 3;
    return 32 * (s & 3) + 8 * kq + 4 * (s >> 2) + r;
}

// ---- weight chunk staging (edge_mlp path): 128 rows x 64 k (16 KB) ----
__device__ __forceinline__ void load_wchunk(const u16* __restrict__ wt, int KPu, int c,
                                            int tid, u16x8 st[4]) {
#pragma unroll
    for (int s = 0; s < 4; ++s) {
        int i = s * NTH + tid;                 // 0..1023
        int n = i >> 3, jj = i & 7;
        st[s] = *(const u16x8*)(wt + (size_t)n * KPu + (c * 8 + jj) * 8);
    }
}
__device__ __forceinline__ void write_wchunk(u16* wb, int tid, const u16x8 st[4]) {
#pragma unroll
    for (int s = 0; s < 4; ++s) {
        int i = s * NTH + tid;
        *(u16x8*)(wb + i * 8) = st[s];
    }
}

template<int NKS>
__device__ __forceinline__ void mfma_chunk(const u16* cur, const bf16x8* afc,
                                           int ml, int kq, f32x4 acc[8]) {
#pragma unroll
    for (int ks = 0; ks < NKS; ++ks) {
        bf16x8 a = afc[ks];
#pragma unroll
        for (int sc = 0; sc < 8; ++sc) {
            bf16x8 b = *(const bf16x8*)&cur[(sc * 16 + ml) * 64 +
                                            (((ks * 4 + kq) ^ (ml & 7)) << 3)];
            acc[sc] = __builtin_amdgcn_mfma_f32_16x16x32_bf16(a, b, acc[sc], 0, 0, 0);
        }
    }
}

// W0-style: stream NCHUNK 64-K chunks through double-buffered LDS (edge path).
template<int NCHUNK, int LAST_NKS>
__device__ __forceinline__ void stream_layer(const u16* __restrict__ wt, int KPu,
                                             const bf16x8* af, u16* wb0, u16* wb1,
                                             int tid, int ml, int kq, f32x4 acc[8]) {
    u16x8 st[4];
    load_wchunk(wt, KPu, 0, tid, st);
    write_wchunk(wb0, tid, st);
    __syncthreads();
#pragma unroll
    for (int c = 0; c < NCHUNK; ++c) {
        u16* cur = (c & 1) ? wb1 : wb0;
        u16* nxt = (c & 1) ? wb0 : wb1;
        if (c + 1 < NCHUNK) load_wchunk(wt, KPu, c + 1, tid, st);   // issue early
        if (c == NCHUNK - 1) mfma_chunk<LAST_NKS>(cur, af + 2 * c, ml, kq, acc);
        else                 mfma_chunk<2>(cur, af + 2 * c, ml, kq, acc);
        if (c + 1 < NCHUNK) write_wchunk(nxt, tid, st);             // write late
        __syncthreads();
    }
}

// K=128 layer: preload both 64-K chunks, single barrier (edge path).
__device__ __forceinline__ void preload2_layer(const u16* __restrict__ wt,
                                               const bf16x8* af, u16* wb0, u16* wb1,
                                               int tid, int ml, int kq, f32x4 acc[8]) {
    u16x8 s0[4], s1[4];
    load_wchunk(wt, 128, 0, tid, s0);
    load_wchunk(wt, 128, 1, tid, s1);
    write_wchunk(wb0, tid, s0);
    write_wchunk(wb1, tid, s1);
    __syncthreads();
    mfma_chunk<2>(wb0, af + 0, ml, kq, acc);
    mfma_chunk<2>(wb1, af + 2, ml, kq, acc);
}

__device__ __forceinline__ void init_acc(const float* __restrict__ b, int ml, f32x4 acc[8]) {
#pragma unroll
    for (int sc = 0; sc < 8; ++sc) {
        float bv = b[sc * 16 + ml];
        acc[sc] = f32x4{bv, bv, bv, bv};
    }
}

// SELU(acc) -> bf16 -> hbuf[.][136] (edge_mlp path only)
__device__ __forceinline__ void store_h_selu(const f32x4 acc[8], u16* hbuf,
                                             int w, int ml, int kq) {
#pragma unroll
    for (int sc = 0; sc < 8; ++sc)
#pragma unroll
        for (int r = 0; r < 4; r += 2) {
            unsigned u = cvt2(selu_f(acc[sc][r]), selu_f(acc[sc][r + 1]));
            int rowb = w * 16 + kq * 4 + r;
            hbuf[rowb * 136 + sc * 16 + ml]       = (u16)u;
            hbuf[(rowb + 1) * 136 + sc * 16 + ml] = (u16)(u >> 16);
        }
}
__device__ __forceinline__ void read_af_h(const u16* hbuf, int w, int ml, int kq,
                                          bf16x8 af[4]) {
#pragma unroll
    for (int f = 0; f < 4; ++f)            // col = f*32 + kq*8
        af[f] = *(const bf16x8*)&hbuf[(w * 16 + ml) * 136 + f * 32 + kq * 8];
}

// ---- prep: fp32 W[K][128] -> bf16 W^T[128][KP], 16B-block XOR(n&7) swizzle.
// m=0 (aW0): col pi(n), bias ab0[pi(n)] injected at k=264.
// m=1 (aW1): col pi(n). m=2 (aW2), m>=3 (eW*): canonical.
// tail block: b1p[i] = ab1[pi(i)].
__global__ void prep_weights(const float* __restrict__ aW0, const float* __restrict__ ab0,
                             const float* __restrict__ aW1, const float* __restrict__ ab1,
                             const float* __restrict__ aW2, const float* __restrict__ eW0,
                             const float* __restrict__ eW1, const float* __restrict__ eW2,
                             u16* __restrict__ dst, float* __restrict__ b1p)
{
    int t = blockIdx.x * 256 + threadIdx.x;
    if (t >= 17408) {                       // tail: permuted b1
        int i = t - 17408;
        if (i < 128) b1p[i] = ab1[pperm(i)];
        return;
    }
    const int nbs[6]  = {40, 16, 16, 32, 16, 16};
    const int Ks[6]   = {264, 128, 128, 256, 128, 128};
    const int offs[6] = {0, 40960, 57344, 73728, 106496, 122880};
    const float* Ws[6] = {aW0, aW1, aW2, eW0, eW1, eW2};
    int m = 0, rem = t;
    for (m = 0; m < 6; ++m) { int c = 128 * nbs[m]; if (rem < c) break; rem -= c; }
    if (m >= 6) return;
    const int nb = nbs[m];
    const int n = rem / nb, j = rem % nb;
    const int c = j >> 3, jj = j & 7;
    const int kb = jj ^ (n & 7);
    const int k0 = c * 64 + kb * 8;
    const int K = Ks[m];
    const float* W = Ws[m];
    const int nc = (m <= 1) ? pperm(n) : n;
    union { u16 u[8]; u16x8 v; } o;
#pragma unroll
    for (int i = 0; i < 8; ++i) {
        int k = k0 + i;
        float fv;
        if (m == 0)      fv = (k < 264) ? aW0[k * H + nc] : (k == 264 ? ab0[nc] : 0.0f);
        else if (m == 1) fv = (k < 128) ? aW1[k * H + nc] : 0.0f;
        else             fv = (k < K) ? W[k * H + n] : 0.0f;
        o.u[i] = f2bf(fv);
    }
    *(u16x8*)&dst[offs[m] + n * (nb * 8) + j * 8] = o.v;
}

// ---- angle gather (x^T as B-operand: lane (ml,kq) holds x[edge ml][k]) ----
__device__ __forceinline__ void issue_gather(float4 r[18],
        const float* __restrict__ e1, const float* __restrict__ e2,
        const float* __restrict__ a12, int e, int rw, int cl, int kq) {
    const float* p1 = e1 + (size_t)rw * H;
    const float* p2 = e2 + (size_t)cl * H;
#pragma unroll
    for (int f = 0; f < 8; ++f) {
        int k0 = f * 32 + kq * 8;
        const float* p = (k0 == 0) ? (a12 + (size_t)e * 8)
                       : (k0 <= 128 ? p1 + (k0 - 8) : p2 + (k0 - 136));
        r[2 * f]     = ld4(p);
        r[2 * f + 1] = ld4(p + 4);
    }
    if (kq == 0) { r[16] = ld4(p2 + 120); r[17] = ld4(p2 + 124); }
}
// af[8]: kq==0 -> e2 tail (k=256..263); kq==1 -> {1.0, 0..} (k=264: bias row);
// kq>=2 -> zeros.
__device__ __forceinline__ void conv_gather(const float4 r[18], bf16x8 af[9], int kq) {
#pragma unroll
    for (int f = 0; f < 8; ++f) af[f] = cvt8(r[2 * f], r[2 * f + 1]);
    if (kq == 0) af[8] = cvt8(r[16], r[17]);
    else if (kq == 1) { bf16x8 o = {(short)0x3F80, 0, 0, 0, 0, 0, 0, 0}; af[8] = o; }
    else { bf16x8 z = {0, 0, 0, 0, 0, 0, 0, 0}; af[8] = z; }
}

// ---- angle MLP: persistent, all-LDS weights, swapped-operand MFMA ----
__global__ __launch_bounds__(512, 1) __attribute__((amdgpu_waves_per_eu(1)))
void angle_mlp(
    const float* __restrict__ e1, const float* __restrict__ e2,
    const float* __restrict__ a12, const int* __restrict__ idx,
    const u16* __restrict__ wt0, const u16* __restrict__ wt1, const u16* __restrict__ wt2,
    const float* __restrict__ b1p, const float* __restrict__ b2g,
    u16* __restrict__ sums, float* __restrict__ cnt, int A)
{
    __shared__ u16 w0s[128 * 320];      // 80 KB
    __shared__ u16 w1s[128 * 128];      // 32 KB
    __shared__ u16 w2s[128 * 128];      // 32 KB
    __shared__ float b1s[128];
    __shared__ float b2s[128];

    const int tid = threadIdx.x;
#pragma unroll
    for (int i = 0; i < 10; ++i) {      // W0: 5120 u16x8
        int j = i * 512 + tid;
        *(u16x8*)&w0s[j * 8] = *(const u16x8*)&wt0[j * 8];
    }
#pragma unroll
    for (int i = 0; i < 4; ++i) {       // W1: 2048 u16x8
        int j = i * 512 + tid;
        *(u16x8*)&w1s[j * 8] = *(const u16x8*)&wt1[j * 8];
    }
#pragma unroll
    for (int i = 0; i < 4; ++i) {       // W2
        int j = i * 512 + tid;
        *(u16x8*)&w2s[j * 8] = *(const u16x8*)&wt2[j * 8];
    }
    if (tid < 128) { b1s[tid] = b1p[tid]; b2s[tid] = b2g[tid]; }
    __syncthreads();                    // only barrier in the kernel

    const int lane = tid & 63;
    const int ml = lane & 15, kq = lane >> 4;
    const int wv = tid >> 6;            // 0..7
    const int NT = A >> 4;              // 25000 tiles of 16 edges
    int t = blockIdx.x * 8 + wv;        // 0..2047

    int e = t * 16 + ml;
    int rw = idx[e];
    int cl = idx[A + e];
    float4 raw[18];
    issue_gather(raw, e1, e2, a12, e, rw, cl, kq);

    while (true) {
        const int tn = t + 2048;
        const bool last = tn >= NT;     // wave-uniform

        bf16x8 af[9];
        conv_gather(raw, af, kq);       // waits on prefetched gather
        if (kq == 0) atomicAdd(&cnt[cl], 1.0f);

        int en = e, rwn = rw, cln = cl;
        if (!last) { en = tn * 16 + ml; rwn = idx[en]; cln = idx[A + en]; }

        f32x4 acc[8];
#pragma unroll
        for (int sc = 0; sc < 8; ++sc) acc[sc] = f32x4{0.f, 0.f, 0.f, 0.f};

        // L0: D0 = W0^T(stored) . x^T ; acc[sc] rows sc*16+kq*4+r, col=edge ml
#pragma unroll
        for (int ks = 0; ks < 9; ++ks) {
            int B = ks * 4 + kq;
            int off = (((B >> 3) * 8) + ((B & 7) ^ (ml & 7))) << 3;
#pragma unroll
            for (int sc = 0; sc < 8; ++sc) {
                bf16x8 a = *(const bf16x8*)&w0s[(sc * 16 + ml) * 320 + off];
                acc[sc] = __builtin_amdgcn_mfma_f32_16x16x32_bf16(a, af[ks], acc[sc], 0, 0, 0);
            }
        }

        if (!last) issue_gather(raw, e1, e2, a12, en, rwn, cln, kq);  // hide HBM lat

        // transition -> L1 (in-lane: pi baked into W0-out/W1-in)
        bf16x8 hq[4];
#pragma unroll
        for (int ks = 0; ks < 4; ++ks) hq[ks] = cvt8selu(acc[ks], acc[ks + 4]);
#pragma unroll
        for (int sc = 0; sc < 8; ++sc) acc[sc] = *(const f32x4*)&b1s[sc * 16 + kq * 4];
#pragma unroll
        for (int ks = 0; ks < 4; ++ks) {
            int B = ks * 4 + kq;
            int off = (((B >> 3) * 8) + ((B & 7) ^ (ml & 7))) << 3;
#pragma unroll
            for (int sc = 0; sc < 8; ++sc) {
                bf16x8 a = *(const bf16x8*)&w1s[(sc * 16 + ml) * 128 + off];
                acc[sc] = __builtin_amdgcn_mfma_f32_16x16x32_bf16(a, hq[ks], acc[sc], 0, 0, 0);
            }
        }

        // transition -> L2 (W2 canonical out)
#pragma unroll
        for (int ks = 0; ks < 4; ++ks) hq[ks] = cvt8selu(acc[ks], acc[ks + 4]);
#pragma unroll
        for (int sc = 0; sc < 8; ++sc) acc[sc] = *(const f32x4*)&b2s[sc * 16 + kq * 4];
#pragma unroll
        for (int ks = 0; ks < 4; ++ks) {
            int B = ks * 4 + kq;
            int off = (((B >> 3) * 8) + ((B & 7) ^ (ml & 7))) << 3;
#pragma unroll
            for (int sc = 0; sc < 8; ++sc) {
                bf16x8 a = *(const bf16x8*)&w2s[(sc * 16 + ml) * 128 + off];
                acc[sc] = __builtin_amdgcn_mfma_f32_16x16x32_bf16(a, hq[ks], acc[sc], 0, 0, 0);
            }
        }

        // scatter: col = own edge ml; rows = canonical hdims sc*16+kq*4+r.
        {
            u16* dst = sums + (size_t)cl * H + kq * 4;
#pragma unroll
            for (int sc = 0; sc < 8; ++sc) {
#pragma unroll
                for (int q = 0; q < 2; ++q) {
                    union { __half2 h; unsigned u; } c;
                    c.h = __floats2half2_rn(acc[sc][2 * q], acc[sc][2 * q + 1]);
                    u16* d = dst + sc * 16 + 2 * q;
                    asm volatile("global_atomic_pk_add_f16 %0, %1, off"
                                 :: "v"(d), "v"(c.u) : "memory");
                }
            }
        }

        if (last) break;
        t = tn; e = en; rw = rwn; cl = cln;
    }
}

// ---- edge MLP (unchanged r5 structure, f16 sums input) ----
__global__ __launch_bounds__(NTH, 3) void edge_mlp(
    const float* __restrict__ e2, const u16* __restrict__ sums,
    const float* __restrict__ cnt,
    const u16* __restrict__ wt0, const u16* __restrict__ wt1, const u16* __restrict__ wt2,
    const float* __restrict__ b0, const float* __restrict__ b1, const float* __restrict__ b2,
    float* __restrict__ out, int E2n)
{
    __shared__ u16 wbuf[2][128 * 64];
    __shared__ u16 hbuf[64 * 136];

    const int tid = threadIdx.x;
    const int lane = tid & 63;
    const int ml = lane & 15, kq = lane >> 4;
    const int w = tid >> 6;
    const int nbase = blockIdx.x * 64;
    const int node = nbase + w * 16 + ml;
    const int nc = node < E2n ? node : E2n - 1;

    const float rcp = 1.0f / fmaxf(cnt[nc], 1.0f);
    // frag f: k0 = f*32 + kq*8; k0<128 -> f16 sums*rcp | else e2[k0-128]
    bf16x8 af[8];
    {
        const u16* ps = sums + (size_t)nc * H;
        const float* p2 = e2 + (size_t)nc * H;
#pragma unroll
        for (int f = 0; f < 8; ++f) {
            int k0 = f * 32 + kq * 8;
            float4 lo, hi;
            if (k0 < 128) {
                u16x8 hv = *(const u16x8*)(ps + k0);
                lo.x = h2f(hv[0]) * rcp; lo.y = h2f(hv[1]) * rcp;
                lo.z = h2f(hv[2]) * rcp; lo.w = h2f(hv[3]) * rcp;
                hi.x = h2f(hv[4]) * rcp; hi.y = h2f(hv[5]) * rcp;
                hi.z = h2f(hv[6]) * rcp; hi.w = h2f(hv[7]) * rcp;
            } else {
                lo = ld4(p2 + (k0 - 128));
                hi = ld4(p2 + (k0 - 124));
            }
            af[f] = cvt8(lo, hi);
        }
    }

    f32x4 acc[8];
    init_acc(b0, ml, acc);
    stream_layer<4, 2>(wt0, 256, af, wbuf[0], wbuf[1], tid, ml, kq, acc);

    store_h_selu(acc, hbuf, w, ml, kq);
    __syncthreads();
    bf16x8 af1[4];
    read_af_h(hbuf, w, ml, kq, af1);
    init_acc(b1, ml, acc);
    preload2_layer(wt1, af1, wbuf[0], wbuf[1], tid, ml, kq, acc);

    __syncthreads();
    store_h_selu(acc, hbuf, w, ml, kq);
    __syncthreads();
    bf16x8 af2[4];
    read_af_h(hbuf, w, ml, kq, af2);
    init_acc(b2, ml, acc);
    preload2_layer(wt2, af2, wbuf[0], wbuf[1], tid, ml, kq, acc);

#pragma unroll
    for (int r = 0; r < 4; ++r) {
        int nrow = nbase + w * 16 + kq * 4 + r;
        if (nrow < E2n) {
            float* dst = out + (size_t)nrow * H + ml;
#pragma unroll
            for (int sc = 0; sc < 8; ++sc)
                dst[sc * 16] = acc[sc][r];
        }
    }
}

extern "C" void kernel_launch(void* const* d_in, const int* in_sizes, int n_in,
                              void* d_out, int out_size, void* d_ws, size_t ws_size,
                              hipStream_t stream)
{
    const float* e1  = (const float*)d_in[0];
    const float* e2  = (const float*)d_in[1];
    const float* a12 = (const float*)d_in[2];
    const int*   idx = (const int*)d_in[3];
    const float* aW0 = (const float*)d_in[4];
    const float* ab0 = (const float*)d_in[5];
    const float* aW1 = (const float*)d_in[6];
    const float* ab1 = (const float*)d_in[7];
    const float* aW2 = (const float*)d_in[8];
    const float* ab2 = (const float*)d_in[9];
    const float* eW0 = (const float*)d_in[10];
    const float* eb0 = (const float*)d_in[11];
    const float* eW1 = (const float*)d_in[12];
    const float* eb1 = (const float*)d_in[13];
    const float* eW2 = (const float*)d_in[14];
    const float* eb2 = (const float*)d_in[15];

    const int E2n = in_sizes[1] / H;   // 100000
    const int A   = in_sizes[2] / 8;   // 400000

    char* ws = (char*)d_ws;
    u16*   wdst   = (u16*)ws;                                // 278528 B
    u16*   sums_h = (u16*)(ws + 278528);                     // f16 [E2][128]
    float* cnt    = (float*)(ws + 278528 + (size_t)E2n * H * 2);
    float* b1p    = (float*)(ws + 278528 + (size_t)E2n * H * 2 + (size_t)E2n * 4);

    hipMemsetAsync(sums_h, 0, (size_t)E2n * H * 2 + (size_t)E2n * 4, stream);
    prep_weights<<<dim3(69), dim3(256), 0, stream>>>(
        aW0, ab0, aW1, ab1, aW2, eW0, eW1, eW2, wdst, b1p);

    angle_mlp<<<dim3(256), dim3(512), 0, stream>>>(
        e1, e2, a12, idx, wdst + 0, wdst + 40960, wdst + 57344,
        b1p, ab2, sums_h, cnt, A);

    edge_mlp<<<dim3((E2n + 63) / 64), dim3(NTH), 0, stream>>>(
        e2, sums_h, cnt, wdst + 73728, wdst + 106496, wdst + 122880,
        eb0, eb1, eb2, (float*)d_out, E2n);
}